// Round 8
// baseline (37.729 us; speedup 1.0000x reference)
//
#include <hip/hip_runtime.h>
#include <cstddef>

// RoIPool: features (B=2, C=256, H=50, W=50) f32, rois (R,4) f32, roi_indices (R,) int
// out (R, C, 7, 7) f32.
// Reference quirk preserved: h-bins from x coords (ri[:,0], ri[:,2]), w-bins from y.
//
// SINGLE fused kernel (no transpose pre-pass, no d_ws, no global sync):
// block = (slice s of 64 channels, roi r), 448 threads = 7 waves.
// For each of the 7 h-bins (ph): stage the bin's rows (<=4) x the ROI's full
// col window (<=19) x 64 channels from NCHW into LDS (coalesced row-segment
// reads; odd channel-stride 65 makes both the w-fastest writes and c-fastest
// reads bank-conflict-free), __syncthreads, then wave pw computes its bin max
// from LDS. Output staged in st[] and written as 7 coalesced nontemporal
// 448-lane stores. Geometry is wave-uniform (readfirstlane -> SGPR branches).
//
// Bounds for this input distribution (proven): Lh,Lw in [4,19] -> per-bin
// span in [1,4]; y1>=0, x2<=49, y2<=49 -> no edge clamps ever trigger.
// Guards (min with HMAX/WMAX) only protect LDS if assumptions break.

namespace {
constexpr int OUTP = 7;
constexpr int BB = 2;
constexpr int CC = 256;
constexpr int HH = 50;
constexpr int WW = 50;
constexpr int HWSZ = HH * WW;
constexpr int CSPLIT = 4;
constexpr int CPS = CC / CSPLIT;  // 64 channels per slice
constexpr float NEGV = -3e38f;
constexpr int WMAX = 20;  // staged cols cap (Lw <= 19)
constexpr int HMAX = 4;   // staged rows cap (per-bin span <= 4)
constexpr int CPAD = 65;  // odd c-stride: conflict-free write (w-varying) & read (c-varying)
}  // namespace

__global__ __launch_bounds__(448, 7) void roipool_fused(
    const float* __restrict__ feat, const float* __restrict__ rois,
    const int* __restrict__ ridx, float* __restrict__ out) {
    __shared__ float buf[HMAX * WMAX * CPAD];  // 20.3 KB window stage
    __shared__ float st[CPS * OUTP * OUTP];    // 12.25 KB output stage

    const int s = blockIdx.x;
    const int r = blockIdx.y;
    const int tid = threadIdx.x;

    const float4 rv = reinterpret_cast<const float4*>(rois)[r];
    int x1 = (int)(rv.x * 0.0625f);
    int y1 = (int)(rv.y * 0.0625f);
    int x2 = (int)(rv.z * 0.0625f);
    int y2 = (int)(rv.w * 0.0625f);
    int b = ridx[r];
    x1 = __builtin_amdgcn_readfirstlane(x1);
    y1 = __builtin_amdgcn_readfirstlane(y1);
    x2 = __builtin_amdgcn_readfirstlane(x2);
    y2 = __builtin_amdgcn_readfirstlane(y2);
    b = __builtin_amdgcn_readfirstlane(b);

    const int Lh = x2 - x1;
    int Lw = y2 - y1;
    if (Lw > WMAX) Lw = WMAX;  // LDS guard (never taken for this distribution)
    const int nwT = Lw;        // staged cols = [y1, y1 + nwT)

    // Load-phase mapping: 32 lanes cover a row segment; 14 segments in flight.
    const int wwi = tid & 31;
    const int sidx = tid >> 5;  // 0..13
    // Compute-phase mapping: lane = channel, wave = pw bin.
    const int c = tid & 63;
    const int pw = __builtin_amdgcn_readfirstlane(tid >> 6);  // 0..6

    const float* fbase = feat + ((size_t)(b * CC + s * CPS) * HH) * WW;

    // Per-wave w-bin geometry (wave-uniform).
    const int aw = (pw * Lw) / OUTP;                      // local col start
    const int ew = ((pw + 1) * Lw + OUTP - 1) / OUTP;     // local col end (<= Lw)

#pragma unroll
    for (int ph = 0; ph < OUTP; ++ph) {
        int hs = x1 + (ph * Lh) / OUTP;
        int he = x1 + ((ph + 1) * Lh + OUTP - 1) / OUTP;
        int nh = he - hs;
        if (nh > HMAX) nh = HMAX;  // LDS guard (never taken)

        __syncthreads();  // prior compute done reading buf before overwrite

        // Stage nh rows x nwT cols x 64 ch. Row segments contiguous in NCHW.
        const float* pbase = fbase + (size_t)hs * WW + y1;
        const int nseg = nh << 6;  // (hh, ci) pairs
        if (wwi < nwT) {
            for (int seg = sidx; seg < nseg; seg += 14) {
                const int ci = seg & 63;
                const int hh = seg >> 6;
                const float v = pbase[(size_t)ci * HWSZ + hh * WW + wwi];
                buf[(hh * WMAX + wwi) * CPAD + ci] = v;
            }
        }
        __syncthreads();

        // Wave pw: max over its bin window from LDS (all bounds wave-uniform).
        float m = NEGV;
        for (int hh = 0; hh < nh; ++hh) {
            for (int w = aw; w < ew; ++w) {
                m = fmaxf(m, buf[(hh * WMAX + w) * CPAD + c]);
            }
        }
        st[c * 49 + ph * OUTP + pw] = m;
    }
    __syncthreads();

    // Coalesced nontemporal copy-out: 3136 floats = 448 threads x 7.
    float* ob = out + (size_t)(r * CC + s * CPS) * (OUTP * OUTP);
#pragma unroll
    for (int k = 0; k < OUTP; ++k) {
        __builtin_nontemporal_store(st[tid + k * 448], ob + tid + k * 448);
    }
}

extern "C" void kernel_launch(void* const* d_in, const int* in_sizes, int n_in,
                              void* d_out, int out_size, void* d_ws, size_t ws_size,
                              hipStream_t stream) {
    const float* features = (const float*)d_in[0];
    const float* rois = (const float*)d_in[1];
    const int* ridx = (const int*)d_in[2];
    float* out = (float*)d_out;
    const int R = in_sizes[1] / 4;

    roipool_fused<<<dim3(CSPLIT, R), 448, 0, stream>>>(features, rois, ridx, out);
}

// Round 9
// 24.013 us; speedup vs baseline: 1.5712x; 1.5712x over previous
//
#include <hip/hip_runtime.h>
#include <cstddef>

// RoIPool: features (B=2, C=256, H=50, W=50) f32, rois (R,4) f32, roi_indices (R,) int
// out (R, C, 7, 7) f32.
// Reference quirk preserved: h-bins from x coords (ri[:,0], ri[:,2]), w-bins from y.
//
// Single fused kernel, ONE barrier per block (R8 post-mortem: 14 barriers +
// tiny phases = latency-bound at 40 us). Block = (slice s of 32 ch, roi r),
// 256 threads. Stage the WHOLE ROI window (<=19 rows x 20 cols x 32 ch,
// 51 KB LDS, 3 blocks/CU) via float4 row segments, one __syncthreads, then
// thread = (channel, bin-group) computes 7 bins each from LDS (odd c-stride
// 399 -> conflict-free) and writes out directly (block covers its contiguous
// 6 KB out chunk; L2 write-back coalesces).
//
// Distribution-proven bounds: Lh, Lw in [4,19]; x1,y1 >= 0; x2,y2 <= 49;
// per-bin span <= 4. Fast path guarded; generic global-read fallback kept.

namespace {
constexpr int OUTP = 7;
constexpr int CC = 256;
constexpr int HH = 50;
constexpr int WW = 50;
constexpr int HWSZ = HH * WW;
constexpr int CSPLIT = 8;
constexpr int CPS = CC / CSPLIT;    // 32 channels per slice
constexpr float NEGV = -3e38f;
constexpr int LMAX = 19;            // max Lh / Lw for fast path
constexpr int RSTR = 21;            // LDS cols per row (20 staged + pad)
constexpr int CSTR = LMAX * RSTR;   // 399 floats per channel; odd -> no bank conflicts
typedef float vf4 __attribute__((ext_vector_type(4), aligned(4)));  // unaligned-safe
}  // namespace

__global__ __launch_bounds__(256, 3) void roipool_fused(
    const float* __restrict__ feat, const float* __restrict__ rois,
    const int* __restrict__ ridx, float* __restrict__ out) {
    __shared__ float buf[CPS * CSTR];  // 51072 B

    const int s = blockIdx.x;  // grid (8, R): linear id % 8 == s -> XCD-pinned slice
    const int r = blockIdx.y;
    const int tid = threadIdx.x;

    const float4 rv = reinterpret_cast<const float4*>(rois)[r];
    int x1 = (int)(rv.x * 0.0625f);
    int y1 = (int)(rv.y * 0.0625f);
    int x2 = (int)(rv.z * 0.0625f);
    int y2 = (int)(rv.w * 0.0625f);
    int b = ridx[r];
    x1 = __builtin_amdgcn_readfirstlane(x1);
    y1 = __builtin_amdgcn_readfirstlane(y1);
    x2 = __builtin_amdgcn_readfirstlane(x2);
    y2 = __builtin_amdgcn_readfirstlane(y2);
    b = __builtin_amdgcn_readfirstlane(b);

    const int Lh = x2 - x1;
    const int Lw = y2 - y1;

    const float* fb = feat + (size_t)(b * CC + s * CPS) * HWSZ;
    float* obase = out + (size_t)(r * CC + s * CPS) * (OUTP * OUTP);

    const bool fast = (Lh >= 1 && Lh <= LMAX && Lw >= 1 && Lw <= LMAX &&
                       x1 >= 0 && y1 >= 0 && x2 < HH && y2 < WW);

    if (fast) {  // block-uniform branch (all operands SGPR)
        // ---- Stage: rows [x1, x1+Lh), cols [y1, y1+20) x 32 ch.
        // Reading cols y1..y1+19 may spill into the next image row: harmless,
        // in-bounds (last staged row <= 48), and compute never reads past Lw.
        {
            const int c = tid >> 3;  // 0..31
            const int j = tid & 7;   // float4 group; j<5 active (20 cols)
            if (j < 5) {
                const float* gp = fb + (size_t)c * HWSZ + (size_t)x1 * WW + y1 + j * 4;
                float* lp = buf + c * CSTR + j * 4;
                for (int row = 0; row < Lh; ++row) {
                    const vf4 v = *reinterpret_cast<const vf4*>(gp + row * WW);
                    float* q = lp + row * RSTR;
                    q[0] = v.x;
                    q[1] = v.y;
                    q[2] = v.z;
                    q[3] = v.w;
                }
            }
        }
        __syncthreads();

        // ---- Compute: thread = (cc in 0..31, q in 0..7); bins q, q+8, ...
        const int cc = tid & 31;
        const int q = tid >> 5;
        const float* cb = buf + cc * CSTR;
        float* ob = obase + (size_t)cc * (OUTP * OUTP);

#pragma unroll
        for (int k = 0; k < 7; ++k) {
            const int bin = q + k * 8;
            if (bin < 49) {
                const int ph = bin / OUTP;  // const-divisor -> mul/shift
                const int pw = bin - ph * OUTP;
                const int h0 = (ph * Lh) / OUTP;
                const int nh = ((ph + 1) * Lh + OUTP - 1) / OUTP - h0;  // 1..4
                const int w0 = (pw * Lw) / OUTP;
                const int nw = ((pw + 1) * Lw + OUTP - 1) / OUTP - w0;  // 1..4
                const float* wb = cb + h0 * RSTR + w0;
                float m = NEGV;
#pragma unroll
                for (int i = 0; i < 4; ++i) {
                    // dup-clamp: out-of-window rows/cols re-read in-window data
                    const int ro = (i < nh ? i : nh - 1) * RSTR;
#pragma unroll
                    for (int jj = 0; jj < 4; ++jj) {
                        const int co = (jj < nw ? jj : nw - 1);
                        m = fmaxf(m, wb[ro + co]);
                    }
                }
                __builtin_nontemporal_store(m, ob + bin);
            }
        }
    } else {
        // ---- Generic fallback: direct global reads (never taken for this
        // input distribution). Empty windows -> NEGV, matching the reference.
        const int cc = tid & 31;
        const int q = tid >> 5;
        const float* cb = fb + (size_t)cc * HWSZ;
        float* ob = obase + (size_t)cc * (OUTP * OUTP);

        for (int k = 0; k < 7; ++k) {
            const int bin = q + k * 8;
            if (bin < 49) {
                const int ph = bin / OUTP;
                const int pw = bin - ph * OUTP;
                int hs = x1 + (ph * Lh) / OUTP;
                int he = x1 + ((ph + 1) * Lh + OUTP - 1) / OUTP;
                int ws = y1 + (pw * Lw) / OUTP;
                int we = y1 + ((pw + 1) * Lw + OUTP - 1) / OUTP;
                hs = hs < 0 ? 0 : hs;
                he = he > HH ? HH : he;
                ws = ws < 0 ? 0 : ws;
                we = we > WW ? WW : we;
                float m = NEGV;
                for (int h = hs; h < he; ++h) {
                    for (int w = ws; w < we; ++w) {
                        m = fmaxf(m, cb[h * WW + w]);
                    }
                }
                ob[bin] = m;
            }
        }
    }
}

extern "C" void kernel_launch(void* const* d_in, const int* in_sizes, int n_in,
                              void* d_out, int out_size, void* d_ws, size_t ws_size,
                              hipStream_t stream) {
    const float* features = (const float*)d_in[0];
    const float* rois = (const float*)d_in[1];
    const int* ridx = (const int*)d_in[2];
    float* out = (float*)d_out;
    const int R = in_sizes[1] / 4;

    roipool_fused<<<dim3(CSPLIT, R), 256, 0, stream>>>(features, rois, ridx, out);
}